// Round 8
// baseline (725.258 us; speedup 1.0000x reference)
//
#include <hip/hip_runtime.h>
#include <math.h>

#define BB 32
#define TT 512
#define DW 128
#define DC 64
#define DD 192
#define HH 128
#define G4 512
#define LL 32

typedef __fp16 h2_t __attribute__((ext_vector_type(2)));

__device__ __forceinline__ h2_t bch2(unsigned int x) { return __builtin_bit_cast(h2_t, x); }

// quad_perm lane-xor via DPP (VALU, not LDS)
__device__ __forceinline__ float qxor1(float x) {
    return __int_as_float(__builtin_amdgcn_update_dpp(0, __float_as_int(x), 0xB1, 0xF, 0xF, true));
}
__device__ __forceinline__ float qxor2(float x) {
    return __int_as_float(__builtin_amdgcn_update_dpp(0, __float_as_int(x), 0x4E, 0xF, 0xF, true));
}
// quad_perm broadcast of lane q (within each quad)
__device__ __forceinline__ float qbcast(float x, int ctrl_imm) {
    switch (ctrl_imm) {
        case 0: return __int_as_float(__builtin_amdgcn_update_dpp(0, __float_as_int(x), 0x00, 0xF, 0xF, true));
        case 1: return __int_as_float(__builtin_amdgcn_update_dpp(0, __float_as_int(x), 0x55, 0xF, 0xF, true));
        case 2: return __int_as_float(__builtin_amdgcn_update_dpp(0, __float_as_int(x), 0xAA, 0xF, 0xF, true));
        default:return __int_as_float(__builtin_amdgcn_update_dpp(0, __float_as_int(x), 0xFF, 0xF, 0xF, true));
    }
}

// ---------------------------------------------------------------------------
// K1: fused embedding-gather + input projection GEMM, f16 dot2 inner loop.
// v3: software-pipelined staging (loads for chunk k+1 issued before compute
// of chunk k -> gather latency hidden under the 256-dot2 compute phase).
// ---------------------------------------------------------------------------
__global__ __launch_bounds__(256) void k_inproj(
    const int* __restrict__ word, const int* __restrict__ charr,
    const float* __restrict__ wemb, const float* __restrict__ cemb,
    const float* __restrict__ Wf, const float* __restrict__ bf,
    const float* __restrict__ Wb, const float* __restrict__ bb,
    float* __restrict__ xpf, float* __restrict__ xpb)
{
    __shared__ __align__(16) h2_t As2[4][132];   // [k-pair][row]
    __shared__ __align__(16) h2_t Bs2[4][132];   // [k-pair][gate-col]
    const int tid = threadIdx.x;
    const int ntile = blockIdx.x;
    const int ctile = blockIdx.y;
    const int dir = ctile >> 2;
    const float* W = dir ? Wb : Wf;
    const float* bias = dir ? bb : bf;
    float* xp = dir ? xpb : xpf;
    const int colbase = (ctile & 3) * 128;

    const int tr = tid >> 4;    // 0..15
    const int tc = tid & 15;    // 0..15

    float acc[8][8];
#pragma unroll
    for (int i = 0; i < 8; ++i)
#pragma unroll
        for (int j = 0; j < 8; ++j) acc[i][j] = 0.f;

    const int lrow = tid >> 1;            // 0..127
    const int lk   = (tid & 1) * 4;       // 0 or 4
    const int kp0  = lk >> 1;             // 0 or 2
    const int nA   = ntile * 128 + lrow;
    const int wi   = word[nA];
    const int ci   = charr[nA];
    const int g    = colbase + lrow;

    // prologue: load chunk 0 (k0 = lk < 128 -> always wordemb)
    float4 av = *(const float4*)(wemb + (size_t)wi * DW + lk);
    float4 bv = *(const float4*)(W + (size_t)g * DD + lk);

    for (int kc = 0; kc < 24; ++kc) {
        __syncthreads();
        As2[kp0 + 0][lrow] = __builtin_amdgcn_cvt_pkrtz(av.x, av.y);
        As2[kp0 + 1][lrow] = __builtin_amdgcn_cvt_pkrtz(av.z, av.w);
        Bs2[kp0 + 0][lrow] = __builtin_amdgcn_cvt_pkrtz(bv.x, bv.y);
        Bs2[kp0 + 1][lrow] = __builtin_amdgcn_cvt_pkrtz(bv.z, bv.w);
        __syncthreads();
        // issue next chunk's loads NOW (in flight across the compute phase)
        const int kcn = (kc + 1 < 24) ? (kc + 1) : 23;
        const int k0n = kcn * 8 + lk;
        float4 avn, bvn;
        if (k0n < DW) avn = *(const float4*)(wemb + (size_t)wi * DW + k0n);
        else          avn = *(const float4*)(cemb + (size_t)ci * DC + (k0n - DW));
        bvn = *(const float4*)(W + (size_t)g * DD + k0n);
#pragma unroll
        for (int kp = 0; kp < 4; ++kp) {
            h2_t __attribute__((aligned(16))) a2[8], b2[8];
            *(uint4*)&a2[0] = *(const uint4*)&As2[kp][tr * 8];
            *(uint4*)&a2[4] = *(const uint4*)&As2[kp][tr * 8 + 4];
            *(uint4*)&b2[0] = *(const uint4*)&Bs2[kp][tc * 8];
            *(uint4*)&b2[4] = *(const uint4*)&Bs2[kp][tc * 8 + 4];
#pragma unroll
            for (int i = 0; i < 8; ++i)
#pragma unroll
                for (int j = 0; j < 8; ++j)
                    acc[i][j] = __builtin_amdgcn_fdot2(a2[i], b2[j], acc[i][j], false);
        }
        av = avn; bv = bvn;
    }
#pragma unroll
    for (int i = 0; i < 8; ++i) {
        const int n  = ntile * 128 + tr * 8 + i;
        const int b_ = n >> 9, t_ = n & 511;
        float* dst = xp + ((size_t)(t_ * BB + b_)) * G4 + colbase + tc * 8;
#pragma unroll
        for (int j = 0; j < 8; ++j) dst[j] = acc[i][j] + bias[colbase + tc * 8 + j];
    }
}

// ---------------------------------------------------------------------------
// K2: LSTM scan v8 — TWO SAMPLES PER BLOCK. 32 blocks = (dir, sample-pair),
// 512 threads, thread (u=tid>>2, ks=tid&3). Shared weight registers (64 VGPR)
// amortized over 2 recurrences; dual-sample interleave gives 8 independent
// dot2 chains (latency covered) and amortizes barrier/ds_read/gate-chain
// latency over 2x useful work.
// ---------------------------------------------------------------------------
__global__ __launch_bounds__(512)
__attribute__((amdgpu_waves_per_eu(2, 2)))
void k_lstm(
    const float* __restrict__ xpf, const float* __restrict__ xpb,
    const float* __restrict__ Whf, const float* __restrict__ Whb,
    float* __restrict__ hf, float* __restrict__ hb)
{
    // [buf][smp][ks*40 + j] f16; per-ks block = 80 B; s0/s1 bases 320 B apart
    // -> all reads conflict-free broadcasts.
    __shared__ __align__(16) __fp16 hsd[2][2][160];
    const int tid = threadIdx.x;
    const int dir = blockIdx.x >> 4;
    const int b0  = (blockIdx.x & 15) * 2;
    const float* xp = dir ? xpb : xpf;
    const float* Wh = dir ? Whb : Whf;
    float* hout = dir ? hb : hf;
    const int ks = tid & 3;          // k-quarter == owned gate id
    const int u  = tid >> 2;         // hidden unit 0..127

    // W_hh[g*128+u][ks*32 .. +31] for g=0..3 as packed half2: 64 VGPRs
    h2_t w2[4][16];
#pragma unroll
    for (int g = 0; g < 4; ++g) {
        const float2* wp = (const float2*)(Wh + (size_t)(g * 128 + u) * HH + ks * 32);
#pragma unroll
        for (int j = 0; j < 16; ++j)
            w2[g][j] = __builtin_amdgcn_cvt_pkrtz(wp[j].x, wp[j].y);
    }

    const float mk0 = (ks == 0) ? 1.f : 0.f;
    const float mk1 = (ks == 1) ? 1.f : 0.f;
    const float mk2 = (ks == 2) ? 1.f : 0.f;
    const float mk3 = (ks == 3) ? 1.f : 0.f;
    const bool istanh = (ks == 2);
    const float GS  = istanh ? 2.f : -1.f;
    const float GC0 = istanh ? 1.f : 0.f;
    const float GC1 = istanh ? -2.f : 1.f;
    const bool ks1 = (ks & 1) != 0;
    const bool ks2b = (ks & 2) != 0;

    if (tid < 160) ((unsigned int*)&hsd[0][0][0])[tid] = 0u;   // zero buf 0 (both samples)
    float c0 = 0.f, c1 = 0.f;
    const int t0 = dir ? (TT - 1) : 0;
    const int tstep = dir ? -1 : 1;
    const int xstride = tstep * BB * G4;
    const int hstride = tstep * BB * HH;
    const float* xqp = xp + ((long long)t0 * BB + b0) * G4 + ks * 128 + u;
    float*       hop = hout + ((long long)t0 * BB + b0) * HH + u;
    float xq0 = xqp[0], xq1 = xqp[G4];
    __syncthreads();

    for (int s = 0; s < TT; ++s) {
        const int rb = s & 1;
        float pA0 = mk0 * xq0, pA1 = mk1 * xq0, pA2 = mk2 * xq0, pA3 = mk3 * xq0;
        float pB0 = mk0 * xq1, pB1 = mk1 * xq1, pB2 = mk2 * xq1, pB3 = mk3 * xq1;
        // prefetch next step's xp (one-past-end lands in adjacent ws buffer)
        xqp += xstride;
        xq0 = xqp[0]; xq1 = xqp[G4];
#pragma unroll
        for (int q = 0; q < 4; ++q) {
            const uint4 hva = *(const uint4*)&hsd[rb][0][ks * 40 + q * 8];
            const uint4 hvb = *(const uint4*)&hsd[rb][1][ks * 40 + q * 8];
            h2_t ha[4], hbv[4];
            ha[0] = bch2(hva.x); ha[1] = bch2(hva.y); ha[2] = bch2(hva.z); ha[3] = bch2(hva.w);
            hbv[0] = bch2(hvb.x); hbv[1] = bch2(hvb.y); hbv[2] = bch2(hvb.z); hbv[3] = bch2(hvb.w);
#pragma unroll
            for (int e = 0; e < 4; ++e) {
                const h2_t ae = ha[e];
                const h2_t be = hbv[e];
                pA0 = __builtin_amdgcn_fdot2(ae, w2[0][q*4+e], pA0, false);
                pB0 = __builtin_amdgcn_fdot2(be, w2[0][q*4+e], pB0, false);
                pA1 = __builtin_amdgcn_fdot2(ae, w2[1][q*4+e], pA1, false);
                pB1 = __builtin_amdgcn_fdot2(be, w2[1][q*4+e], pB1, false);
                pA2 = __builtin_amdgcn_fdot2(ae, w2[2][q*4+e], pA2, false);
                pB2 = __builtin_amdgcn_fdot2(be, w2[2][q*4+e], pB2, false);
                pA3 = __builtin_amdgcn_fdot2(ae, w2[3][q*4+e], pA3, false);
                pB3 = __builtin_amdgcn_fdot2(be, w2[3][q*4+e], pB3, false);
            }
        }
        // quad butterflies (independent across 8 accumulators)
        pA0 += qxor1(pA0); pB0 += qxor1(pB0);
        pA1 += qxor1(pA1); pB1 += qxor1(pB1);
        pA2 += qxor1(pA2); pB2 += qxor1(pB2);
        pA3 += qxor1(pA3); pB3 += qxor1(pB3);
        pA0 += qxor2(pA0); pB0 += qxor2(pB0);
        pA1 += qxor2(pA1); pB1 += qxor2(pB1);
        pA2 += qxor2(pA2); pB2 += qxor2(pB2);
        pA3 += qxor2(pA3); pB3 += qxor2(pB3);
        // lane ks computes its gate's nonlinearity for BOTH samples
        const float pa0 = ks1 ? pA1 : pA0;
        const float pb0 = ks1 ? pA3 : pA2;
        const float psel0 = ks2b ? pb0 : pa0;
        const float pa1 = ks1 ? pB1 : pB0;
        const float pb1 = ks1 ? pB3 : pB2;
        const float psel1 = ks2b ? pb1 : pa1;
        const float val0 = GC0 + GC1 * __builtin_amdgcn_rcpf(1.f + __expf(GS * psel0));
        const float val1 = GC0 + GC1 * __builtin_amdgcn_rcpf(1.f + __expf(GS * psel1));
        const float gi0 = qbcast(val0, 0), gi1 = qbcast(val1, 0);
        const float gf0 = qbcast(val0, 1), gf1 = qbcast(val1, 1);
        const float gg0 = qbcast(val0, 2), gg1 = qbcast(val1, 2);
        const float go0 = qbcast(val0, 3), go1 = qbcast(val1, 3);
        c0 = gf0 * c0 + gi0 * gg0;
        c1 = gf1 * c1 + gi1 * gg1;
        const float tc0 = 1.f - 2.f * __builtin_amdgcn_rcpf(1.f + __expf(2.f * c0));
        const float tc1 = 1.f - 2.f * __builtin_amdgcn_rcpf(1.f + __expf(2.f * c1));
        const float hv0 = go0 * tc0;
        const float hv1 = go1 * tc1;
        if (ks == 0) {
            hsd[rb ^ 1][0][(u >> 5) * 40 + (u & 31)] = (__fp16)hv0;
            hsd[rb ^ 1][1][(u >> 5) * 40 + (u & 31)] = (__fp16)hv1;
            hop[0]  = hv0;
            hop[HH] = hv1;
        }
        hop += hstride;
        // raw barrier: order only LDS (lgkm); global store + prefetch stay
        // in flight.
        __builtin_amdgcn_sched_barrier(0);
        asm volatile("s_waitcnt lgkmcnt(0)");
        __builtin_amdgcn_s_barrier();
        __builtin_amdgcn_sched_barrier(0);
    }
}

// ---------------------------------------------------------------------------
// K3: emit[t][b][l] = (concat(hf,hb)[t][b][:] . W_out[l,:] + b_out[l]) * mask
// ---------------------------------------------------------------------------
__global__ __launch_bounds__(1024) void k_emit(
    const float* __restrict__ hf, const float* __restrict__ hb,
    const float* __restrict__ Wout, const float* __restrict__ bout,
    const int* __restrict__ charr, float* __restrict__ emit)
{
    __shared__ __align__(16) float hsm[BB * 256];
    __shared__ __align__(16) float wsm[LL * 260];
    const int t = blockIdx.x;
    const int tid = threadIdx.x;
    for (int idx = tid; idx < BB * 256; idx += 1024) {
        const int b_ = idx >> 8, u = idx & 255;
        hsm[idx] = (u < HH) ? hf[((size_t)t * BB + b_) * HH + u]
                            : hb[((size_t)t * BB + b_) * HH + (u - HH)];
    }
    for (int idx = tid; idx < LL * 256; idx += 1024) {
        const int l = idx >> 8, u = idx & 255;
        wsm[l * 260 + u] = Wout[idx];
    }
    __syncthreads();
    const int b_ = tid >> 5, l = tid & 31;
    float acc = bout[l];
#pragma unroll 8
    for (int q = 0; q < 64; ++q) {
        const float4 h4 = *(const float4*)&hsm[b_ * 256 + q * 4];
        const float4 w4 = *(const float4*)&wsm[l * 260 + q * 4];
        acc += h4.x * w4.x + h4.y * w4.y + h4.z * w4.z + h4.w * w4.w;
    }
    const float m = (charr[b_ * TT + t] > 0) ? 1.f : 0.f;
    emit[((size_t)t * BB + b_) * LL + l] = acc * m;
}

// ---------------------------------------------------------------------------
// K4: CRF forward v2 — LINEAR-space with periodic renorm.
// ---------------------------------------------------------------------------
__global__ __launch_bounds__(64) void k_crf(
    const float* __restrict__ emit, const int* __restrict__ charr,
    const float* __restrict__ trans, const float* __restrict__ startv,
    const float* __restrict__ endv, float* __restrict__ logZ)
{
    const int tid = threadIdx.x;             // lanes 32..63 mirror lanes 0..31
    const int b_ = blockIdx.x;
    const int j = tid & 31;
    float et[32];
#pragma unroll
    for (int i = 0; i < 32; ++i) et[i] = __expf(trans[i * LL + j]);

    const float a0 = startv[j] + emit[(size_t)b_ * LL + j];
    float M = a0;
    M = fmaxf(M, __shfl_xor(M, 16));
    M = fmaxf(M, __shfl_xor(M, 8));
    M = fmaxf(M, __shfl_xor(M, 4));
    M = fmaxf(M, __shfl_xor(M, 2));
    M = fmaxf(M, __shfl_xor(M, 1));
    float A = __expf(a0 - M);
    float logsc = M;

    float e_nx = emit[((size_t)1 * BB + b_) * LL + j];
    int   m_nx = charr[b_ * TT + 1];

    for (int t = 1; t < TT; ++t) {
        const float ee = __expf(e_nx);       // off critical chain (prefetched)
        const int m_cur = m_nx;
        if (t + 1 < TT) {
            e_nx = emit[((size_t)(t + 1) * BB + b_) * LL + j];
            m_nx = charr[b_ * TT + t + 1];
        }
        float s0 = 0.f, s1 = 0.f, s2 = 0.f, s3 = 0.f;
#pragma unroll
        for (int i = 0; i < 32; i += 4) {
            s0 = fmaf(__shfl(A, i    ), et[i    ], s0);
            s1 = fmaf(__shfl(A, i + 1), et[i + 1], s1);
            s2 = fmaf(__shfl(A, i + 2), et[i + 2], s2);
            s3 = fmaf(__shfl(A, i + 3), et[i + 3], s3);
        }
        const float Anew = ((s0 + s1) + (s2 + s3)) * ee;
        A = (m_cur > 0) ? Anew : A;
        if ((t & 7) == 0) {                  // renorm every 8 steps
            float S = A;
            S = fmaxf(S, __shfl_xor(S, 16));
            S = fmaxf(S, __shfl_xor(S, 8));
            S = fmaxf(S, __shfl_xor(S, 4));
            S = fmaxf(S, __shfl_xor(S, 2));
            S = fmaxf(S, __shfl_xor(S, 1));
            A *= __builtin_amdgcn_rcpf(S);
            logsc += __logf(S);
        }
    }
    // finalize: alpha_j = log(A_j) + logsc; logZ = LSE_j(alpha_j + end_j)
    const float z = __logf(A) + logsc + endv[j];
    float Mz = z;
    Mz = fmaxf(Mz, __shfl_xor(Mz, 16));
    Mz = fmaxf(Mz, __shfl_xor(Mz, 8));
    Mz = fmaxf(Mz, __shfl_xor(Mz, 4));
    Mz = fmaxf(Mz, __shfl_xor(Mz, 2));
    Mz = fmaxf(Mz, __shfl_xor(Mz, 1));
    float sz = __expf(z - Mz);
    sz += __shfl_xor(sz, 16);
    sz += __shfl_xor(sz, 8);
    sz += __shfl_xor(sz, 4);
    sz += __shfl_xor(sz, 2);
    sz += __shfl_xor(sz, 1);
    if (tid == 0) logZ[b_] = Mz + __logf(sz);
}

// ---------------------------------------------------------------------------
// K5: gold path score + final output scalar.
// ---------------------------------------------------------------------------
__global__ __launch_bounds__(1024) void k_gold(
    const float* __restrict__ emit, const int* __restrict__ charr,
    const int* __restrict__ y, const float* __restrict__ trans,
    const float* __restrict__ startv, const float* __restrict__ endv,
    const float* __restrict__ logZ, float* __restrict__ out)
{
    __shared__ float red[BB];
    const int tid = threadIdx.x;
    const int b_ = tid >> 5, l = tid & 31;
    float sc = 0.f;
    int ms = 0;
    for (int t = l; t < TT; t += 32) {
        const int yv = y[b_ * TT + t];
        const int m = (charr[b_ * TT + t] > 0);
        if (m) { sc += emit[((size_t)t * BB + b_) * LL + yv]; ms++; }
        if (t + 1 < TT) {
            const int mn = (charr[b_ * TT + t + 1] > 0);
            if (mn) sc += trans[yv * LL + y[b_ * TT + t + 1]];
        }
    }
#pragma unroll
    for (int o = 16; o; o >>= 1) {
        sc += __shfl_xor(sc, o);
        ms += __shfl_xor(ms, o);
    }
    if (l == 0) {
        int last = ms - 1;
        if (last < 0) last = 0;
        const float gold = startv[y[b_ * TT]] + sc + endv[y[b_ * TT + last]];
        red[b_] = logZ[b_] - gold;
    }
    __syncthreads();
    if (tid == 0) {
        float tot = 0.f;
#pragma unroll
        for (int i = 0; i < BB; ++i) tot += red[i];
        out[0] = tot;
    }
}

extern "C" void kernel_launch(void* const* d_in, const int* in_sizes, int n_in,
                              void* d_out, int out_size, void* d_ws, size_t ws_size,
                              hipStream_t stream) {
    (void)in_sizes; (void)n_in; (void)out_size; (void)ws_size;
    const int*   word  = (const int*)d_in[0];
    const int*   charr = (const int*)d_in[1];
    const int*   yv    = (const int*)d_in[2];
    const float* wemb  = (const float*)d_in[3];
    const float* cemb  = (const float*)d_in[4];
    const float* Wihf  = (const float*)d_in[5];
    const float* Whhf  = (const float*)d_in[6];
    const float* bf    = (const float*)d_in[7];
    const float* Wihb  = (const float*)d_in[8];
    const float* Whhb  = (const float*)d_in[9];
    const float* bb    = (const float*)d_in[10];
    const float* Wout  = (const float*)d_in[11];
    const float* bout  = (const float*)d_in[12];
    const float* trans = (const float*)d_in[13];
    const float* startv= (const float*)d_in[14];
    const float* endv  = (const float*)d_in[15];

    float* ws   = (float*)d_ws;
    float* xpf  = ws;                       // [T][B][512]
    float* xpb  = xpf + (size_t)TT * BB * G4;
    float* hf   = xpb + (size_t)TT * BB * G4;   // [T][B][128]
    float* hb   = hf + (size_t)TT * BB * HH;
    float* emit = hb + (size_t)TT * BB * HH;    // [T][B][32]
    float* logZ = emit + (size_t)TT * BB * LL;  // [32]

    k_inproj<<<dim3(128, 8), 256, 0, stream>>>(word, charr, wemb, cemb,
                                               Wihf, bf, Wihb, bb, xpf, xpb);
    k_lstm<<<32, 512, 0, stream>>>(xpf, xpb, Whhf, Whhb, hf, hb);
    k_emit<<<TT, 1024, 0, stream>>>(hf, hb, Wout, bout, charr, emit);
    k_crf<<<32, 64, 0, stream>>>(emit, charr, trans, startv, endv, logZ);
    k_gold<<<1, 1024, 0, stream>>>(emit, charr, yv, trans, startv, endv, logZ,
                                   (float*)d_out);
}

// Round 9
// 521.899 us; speedup vs baseline: 1.3897x; 1.3897x over previous
//
#include <hip/hip_runtime.h>
#include <math.h>

#define BB 32
#define TT 512
#define DW 128
#define DC 64
#define DD 192
#define HH 128
#define G4 512
#define LL 32

typedef __fp16 h2_t __attribute__((ext_vector_type(2)));

__device__ __forceinline__ h2_t bch2(unsigned int x) { return __builtin_bit_cast(h2_t, x); }

// quad_perm broadcast of lane q (within each quad)
__device__ __forceinline__ float qbcast(float x, int ctrl_imm) {
    switch (ctrl_imm) {
        case 0: return __int_as_float(__builtin_amdgcn_update_dpp(0, __float_as_int(x), 0x00, 0xF, 0xF, true));
        case 1: return __int_as_float(__builtin_amdgcn_update_dpp(0, __float_as_int(x), 0x55, 0xF, 0xF, true));
        case 2: return __int_as_float(__builtin_amdgcn_update_dpp(0, __float_as_int(x), 0xAA, 0xF, 0xF, true));
        default:return __int_as_float(__builtin_amdgcn_update_dpp(0, __float_as_int(x), 0xFF, 0xF, 0xF, true));
    }
}

// rational tanh: Pade 7/6, input clamped to [-8,8]; |err| < 3e-3 over range.
__device__ __forceinline__ float rtanh(float x) {
    x = fminf(fmaxf(x, -8.f), 8.f);
    const float x2 = x * x;
    const float pa = 378.f + x2;
    const float pb = fmaf(x2, pa, 17325.f);
    const float pc = fmaf(x2, pb, 135135.f);
    const float qa = fmaf(x2, 28.f, 3150.f);
    const float qb = fmaf(x2, qa, 62370.f);
    const float qq = fmaf(x2, qb, 135135.f);
    return x * pc * __builtin_amdgcn_rcpf(qq);
}

// ---------------------------------------------------------------------------
// K1: fused embedding-gather + input projection GEMM, f16 dot2, pipelined.
// ---------------------------------------------------------------------------
__global__ __launch_bounds__(256) void k_inproj(
    const int* __restrict__ word, const int* __restrict__ charr,
    const float* __restrict__ wemb, const float* __restrict__ cemb,
    const float* __restrict__ Wf, const float* __restrict__ bf,
    const float* __restrict__ Wb, const float* __restrict__ bb,
    float* __restrict__ xpf, float* __restrict__ xpb)
{
    __shared__ __align__(16) h2_t As2[4][132];   // [k-pair][row]
    __shared__ __align__(16) h2_t Bs2[4][132];   // [k-pair][gate-col]
    const int tid = threadIdx.x;
    const int ntile = blockIdx.x;
    const int ctile = blockIdx.y;
    const int dir = ctile >> 2;
    const float* W = dir ? Wb : Wf;
    const float* bias = dir ? bb : bf;
    float* xp = dir ? xpb : xpf;
    const int colbase = (ctile & 3) * 128;

    const int tr = tid >> 4;    // 0..15
    const int tc = tid & 15;    // 0..15

    float acc[8][8];
#pragma unroll
    for (int i = 0; i < 8; ++i)
#pragma unroll
        for (int j = 0; j < 8; ++j) acc[i][j] = 0.f;

    const int lrow = tid >> 1;            // 0..127
    const int lk   = (tid & 1) * 4;       // 0 or 4
    const int kp0  = lk >> 1;             // 0 or 2
    const int nA   = ntile * 128 + lrow;
    const int wi   = word[nA];
    const int ci   = charr[nA];
    const int g    = colbase + lrow;

    // prologue: load chunk 0 (k0 = lk < 128 -> always wordemb)
    float4 av = *(const float4*)(wemb + (size_t)wi * DW + lk);
    float4 bv = *(const float4*)(W + (size_t)g * DD + lk);

    for (int kc = 0; kc < 24; ++kc) {
        __syncthreads();
        As2[kp0 + 0][lrow] = __builtin_amdgcn_cvt_pkrtz(av.x, av.y);
        As2[kp0 + 1][lrow] = __builtin_amdgcn_cvt_pkrtz(av.z, av.w);
        Bs2[kp0 + 0][lrow] = __builtin_amdgcn_cvt_pkrtz(bv.x, bv.y);
        Bs2[kp0 + 1][lrow] = __builtin_amdgcn_cvt_pkrtz(bv.z, bv.w);
        __syncthreads();
        // issue next chunk's loads NOW (in flight across the compute phase)
        const int kcn = (kc + 1 < 24) ? (kc + 1) : 23;
        const int k0n = kcn * 8 + lk;
        float4 avn, bvn;
        if (k0n < DW) avn = *(const float4*)(wemb + (size_t)wi * DW + k0n);
        else          avn = *(const float4*)(cemb + (size_t)ci * DC + (k0n - DW));
        bvn = *(const float4*)(W + (size_t)g * DD + k0n);
#pragma unroll
        for (int kp = 0; kp < 4; ++kp) {
            h2_t __attribute__((aligned(16))) a2[8], b2[8];
            *(uint4*)&a2[0] = *(const uint4*)&As2[kp][tr * 8];
            *(uint4*)&a2[4] = *(const uint4*)&As2[kp][tr * 8 + 4];
            *(uint4*)&b2[0] = *(const uint4*)&Bs2[kp][tc * 8];
            *(uint4*)&b2[4] = *(const uint4*)&Bs2[kp][tc * 8 + 4];
#pragma unroll
            for (int i = 0; i < 8; ++i)
#pragma unroll
                for (int j = 0; j < 8; ++j)
                    acc[i][j] = __builtin_amdgcn_fdot2(a2[i], b2[j], acc[i][j], false);
        }
        av = avn; bv = bvn;
    }
#pragma unroll
    for (int i = 0; i < 8; ++i) {
        const int n  = ntile * 128 + tr * 8 + i;
        const int b_ = n >> 9, t_ = n & 511;
        float* dst = xp + ((size_t)(t_ * BB + b_)) * G4 + colbase + tc * 8;
#pragma unroll
        for (int j = 0; j < 8; ++j) dst[j] = acc[i][j] + bias[colbase + tc * 8 + j];
    }
}

// ---------------------------------------------------------------------------
// K2: LSTM scan v9. 64 blocks = (dir, sample), 512 threads.
// Lane = (u = tid>>2, ks = tid&3) owns gate ks of unit u over FULL K=128:
//  - 64 h2 weight VGPRs (full W row), acc count 1 (more headroom than R7)
//  - NO butterfly, no gate masks: xq is the direct dot-product init
//  - h in LDS [2][128] f16; reads are uniform-address ds_read_b128
//    broadcasts (conflict-free by definition)
//  - rational sigmoid/tanh (1 rcp + ~8 fma) instead of exp+rcp
// ---------------------------------------------------------------------------
__global__ __launch_bounds__(512)
__attribute__((amdgpu_waves_per_eu(2, 2)))
void k_lstm(
    const float* __restrict__ xpf, const float* __restrict__ xpb,
    const float* __restrict__ Whf, const float* __restrict__ Whb,
    float* __restrict__ hf, float* __restrict__ hb)
{
    __shared__ __align__(16) __fp16 hsd[2][HH];
    const int tid = threadIdx.x;
    const int dir = blockIdx.x >> 5;
    const int b_  = blockIdx.x & 31;
    const float* xp = dir ? xpb : xpf;
    const float* Wh = dir ? Whb : Whf;
    float* hout = dir ? hb : hf;
    const int ks = tid & 3;          // owned gate id
    const int u  = tid >> 2;         // hidden unit 0..127

    // full W_hh row of (gate ks, unit u): 128 f16 = 64 h2 = 64 VGPRs
    h2_t w2[64];
    {
        const float2* wp = (const float2*)(Wh + (size_t)(ks * 128 + u) * HH);
#pragma unroll
        for (int j = 0; j < 64; ++j)
            w2[j] = __builtin_amdgcn_cvt_pkrtz(wp[j].x, wp[j].y);
    }

    // sigmoid(x) = 0.5 + 0.5*tanh(0.5x); tanh(x) = tanh(x)
    const bool istanh = (ks == 2);
    const float SC = istanh ? 1.f : 0.5f;
    const float C0 = istanh ? 0.f : 0.5f;
    const float C1 = istanh ? 1.f : 0.5f;

    if (tid < 64) ((unsigned int*)&hsd[0][0])[tid] = 0u;   // zero buffer 0
    float c = 0.f;
    const int t0 = dir ? (TT - 1) : 0;
    const int tstep = dir ? -1 : 1;
    const int xstride = tstep * BB * G4;
    const int hstride = tstep * BB * HH;
    const float* xqp = xp + ((long long)t0 * BB + b_) * G4 + ks * 128 + u;
    float*       hop = hout + ((long long)t0 * BB + b_) * HH + u;
    float xq = *xqp;
    __syncthreads();

    for (int s = 0; s < TT; ++s) {
        const int rb = s & 1;
        float p = xq;
        // prefetch next xp now (one-past-end lands in adjacent ws buffer)
        xqp += xstride;
        xq = *xqp;
#pragma unroll
        for (int q = 0; q < 16; ++q) {
            const uint4 hv = *(const uint4*)&hsd[rb][q * 8];
            p = __builtin_amdgcn_fdot2(bch2(hv.x), w2[q * 4 + 0], p, false);
            p = __builtin_amdgcn_fdot2(bch2(hv.y), w2[q * 4 + 1], p, false);
            p = __builtin_amdgcn_fdot2(bch2(hv.z), w2[q * 4 + 2], p, false);
            p = __builtin_amdgcn_fdot2(bch2(hv.w), w2[q * 4 + 3], p, false);
        }
        // lane's own gate nonlinearity (rational), then quad regather
        const float val = fmaf(rtanh(SC * p), C1, C0);
        const float gi = qbcast(val, 0);
        const float gf = qbcast(val, 1);
        const float gg = qbcast(val, 2);
        const float go = qbcast(val, 3);
        c = gf * c + gi * gg;
        const float hv_ = go * rtanh(c);
        if (ks == 0) {
            hsd[rb ^ 1][u] = (__fp16)hv_;
            *hop = hv_;
        }
        hop += hstride;
        // raw barrier: order only LDS (lgkm); global store + prefetch stay
        // in flight (no vmcnt drain).
        __builtin_amdgcn_sched_barrier(0);
        asm volatile("s_waitcnt lgkmcnt(0)");
        __builtin_amdgcn_s_barrier();
        __builtin_amdgcn_sched_barrier(0);
    }
}

// ---------------------------------------------------------------------------
// K3: emit[t][b][l] = (concat(hf,hb)[t][b][:] . W_out[l,:] + b_out[l]) * mask
// ---------------------------------------------------------------------------
__global__ __launch_bounds__(1024) void k_emit(
    const float* __restrict__ hf, const float* __restrict__ hb,
    const float* __restrict__ Wout, const float* __restrict__ bout,
    const int* __restrict__ charr, float* __restrict__ emit)
{
    __shared__ __align__(16) float hsm[BB * 256];
    __shared__ __align__(16) float wsm[LL * 260];
    const int t = blockIdx.x;
    const int tid = threadIdx.x;
    for (int idx = tid; idx < BB * 256; idx += 1024) {
        const int b_ = idx >> 8, u = idx & 255;
        hsm[idx] = (u < HH) ? hf[((size_t)t * BB + b_) * HH + u]
                            : hb[((size_t)t * BB + b_) * HH + (u - HH)];
    }
    for (int idx = tid; idx < LL * 256; idx += 1024) {
        const int l = idx >> 8, u = idx & 255;
        wsm[l * 260 + u] = Wout[idx];
    }
    __syncthreads();
    const int b_ = tid >> 5, l = tid & 31;
    float acc = bout[l];
#pragma unroll 8
    for (int q = 0; q < 64; ++q) {
        const float4 h4 = *(const float4*)&hsm[b_ * 256 + q * 4];
        const float4 w4 = *(const float4*)&wsm[l * 260 + q * 4];
        acc += h4.x * w4.x + h4.y * w4.y + h4.z * w4.z + h4.w * w4.w;
    }
    const float m = (charr[b_ * TT + t] > 0) ? 1.f : 0.f;
    emit[((size_t)t * BB + b_) * LL + l] = acc * m;
}

// ---------------------------------------------------------------------------
// K4: CRF forward v3 — linear-space + readlane matvec (no ds_bpermute).
// Lanes 32..63 mirror lanes 0..31, so readlane(A, i) for literal i in [0,32)
// is correct for the whole wave and compiles to v_readlane (no LDS pipe).
// ---------------------------------------------------------------------------
__global__ __launch_bounds__(64) void k_crf(
    const float* __restrict__ emit, const int* __restrict__ charr,
    const float* __restrict__ trans, const float* __restrict__ startv,
    const float* __restrict__ endv, float* __restrict__ logZ)
{
    const int tid = threadIdx.x;             // lanes 32..63 mirror lanes 0..31
    const int b_ = blockIdx.x;
    const int j = tid & 31;
    float et[32];
#pragma unroll
    for (int i = 0; i < 32; ++i) et[i] = __expf(trans[i * LL + j]);

    const float a0 = startv[j] + emit[(size_t)b_ * LL + j];
    float M = a0;
    M = fmaxf(M, __shfl_xor(M, 16));
    M = fmaxf(M, __shfl_xor(M, 8));
    M = fmaxf(M, __shfl_xor(M, 4));
    M = fmaxf(M, __shfl_xor(M, 2));
    M = fmaxf(M, __shfl_xor(M, 1));
    float A = __expf(a0 - M);
    float logsc = M;

    float e_nx = emit[((size_t)1 * BB + b_) * LL + j];
    int   m_nx = charr[b_ * TT + 1];

    for (int t = 1; t < TT; ++t) {
        const float ee = __expf(e_nx);       // off critical chain (prefetched)
        const int m_cur = m_nx;
        if (t + 1 < TT) {
            e_nx = emit[((size_t)(t + 1) * BB + b_) * LL + j];
            m_nx = charr[b_ * TT + t + 1];
        }
        float s0 = 0.f, s1 = 0.f, s2 = 0.f, s3 = 0.f;
#pragma unroll
        for (int i = 0; i < 32; i += 4) {
            s0 = fmaf(__int_as_float(__builtin_amdgcn_readlane(__float_as_int(A), i    )), et[i    ], s0);
            s1 = fmaf(__int_as_float(__builtin_amdgcn_readlane(__float_as_int(A), i + 1)), et[i + 1], s1);
            s2 = fmaf(__int_as_float(__builtin_amdgcn_readlane(__float_as_int(A), i + 2)), et[i + 2], s2);
            s3 = fmaf(__int_as_float(__builtin_amdgcn_readlane(__float_as_int(A), i + 3)), et[i + 3], s3);
        }
        const float Anew = ((s0 + s1) + (s2 + s3)) * ee;
        A = (m_cur > 0) ? Anew : A;
        if ((t & 7) == 0) {                  // renorm every 8 steps
            float S = A;
            S = fmaxf(S, __shfl_xor(S, 16));
            S = fmaxf(S, __shfl_xor(S, 8));
            S = fmaxf(S, __shfl_xor(S, 4));
            S = fmaxf(S, __shfl_xor(S, 2));
            S = fmaxf(S, __shfl_xor(S, 1));
            A *= __builtin_amdgcn_rcpf(S);
            logsc += __logf(S);
        }
    }
    // finalize: alpha_j = log(A_j) + logsc; logZ = LSE_j(alpha_j + end_j)
    const float z = __logf(A) + logsc + endv[j];
    float Mz = z;
    Mz = fmaxf(Mz, __shfl_xor(Mz, 16));
    Mz = fmaxf(Mz, __shfl_xor(Mz, 8));
    Mz = fmaxf(Mz, __shfl_xor(Mz, 4));
    Mz = fmaxf(Mz, __shfl_xor(Mz, 2));
    Mz = fmaxf(Mz, __shfl_xor(Mz, 1));
    float sz = __expf(z - Mz);
    sz += __shfl_xor(sz, 16);
    sz += __shfl_xor(sz, 8);
    sz += __shfl_xor(sz, 4);
    sz += __shfl_xor(sz, 2);
    sz += __shfl_xor(sz, 1);
    if (tid == 0) logZ[b_] = Mz + __logf(sz);
}

// ---------------------------------------------------------------------------
// K5: gold path score + final output scalar.
// ---------------------------------------------------------------------------
__global__ __launch_bounds__(1024) void k_gold(
    const float* __restrict__ emit, const int* __restrict__ charr,
    const int* __restrict__ y, const float* __restrict__ trans,
    const float* __restrict__ startv, const float* __restrict__ endv,
    const float* __restrict__ logZ, float* __restrict__ out)
{
    __shared__ float red[BB];
    const int tid = threadIdx.x;
    const int b_ = tid >> 5, l = tid & 31;
    float sc = 0.f;
    int ms = 0;
    for (int t = l; t < TT; t += 32) {
        const int yv = y[b_ * TT + t];
        const int m = (charr[b_ * TT + t] > 0);
        if (m) { sc += emit[((size_t)t * BB + b_) * LL + yv]; ms++; }
        if (t + 1 < TT) {
            const int mn = (charr[b_ * TT + t + 1] > 0);
            if (mn) sc += trans[yv * LL + y[b_ * TT + t + 1]];
        }
    }
#pragma unroll
    for (int o = 16; o; o >>= 1) {
        sc += __shfl_xor(sc, o);
        ms += __shfl_xor(ms, o);
    }
    if (l == 0) {
        int last = ms - 1;
        if (last < 0) last = 0;
        const float gold = startv[y[b_ * TT]] + sc + endv[y[b_ * TT + last]];
        red[b_] = logZ[b_] - gold;
    }
    __syncthreads();
    if (tid == 0) {
        float tot = 0.f;
#pragma unroll
        for (int i = 0; i < BB; ++i) tot += red[i];
        out[0] = tot;
    }
}

extern "C" void kernel_launch(void* const* d_in, const int* in_sizes, int n_in,
                              void* d_out, int out_size, void* d_ws, size_t ws_size,
                              hipStream_t stream) {
    (void)in_sizes; (void)n_in; (void)out_size; (void)ws_size;
    const int*   word  = (const int*)d_in[0];
    const int*   charr = (const int*)d_in[1];
    const int*   yv    = (const int*)d_in[2];
    const float* wemb  = (const float*)d_in[3];
    const float* cemb  = (const float*)d_in[4];
    const float* Wihf  = (const float*)d_in[5];
    const float* Whhf  = (const float*)d_in[6];
    const float* bf    = (const float*)d_in[7];
    const float* Wihb  = (const float*)d_in[8];
    const float* Whhb  = (const float*)d_in[9];
    const float* bb    = (const float*)d_in[10];
    const float* Wout  = (const float*)d_in[11];
    const float* bout  = (const float*)d_in[12];
    const float* trans = (const float*)d_in[13];
    const float* startv= (const float*)d_in[14];
    const float* endv  = (const float*)d_in[15];

    float* ws   = (float*)d_ws;
    float* xpf  = ws;                       // [T][B][512]
    float* xpb  = xpf + (size_t)TT * BB * G4;
    float* hf   = xpb + (size_t)TT * BB * G4;   // [T][B][128]
    float* hb   = hf + (size_t)TT * BB * HH;
    float* emit = hb + (size_t)TT * BB * HH;    // [T][B][32]
    float* logZ = emit + (size_t)TT * BB * LL;  // [32]

    k_inproj<<<dim3(128, 8), 256, 0, stream>>>(word, charr, wemb, cemb,
                                               Wihf, bf, Wihb, bb, xpf, xpb);
    k_lstm<<<64, 512, 0, stream>>>(xpf, xpb, Whhf, Whhb, hf, hb);
    k_emit<<<TT, 1024, 0, stream>>>(hf, hb, Wout, bout, charr, emit);
    k_crf<<<32, 64, 0, stream>>>(emit, charr, trans, startv, endv, logZ);
    k_gold<<<1, 1024, 0, stream>>>(emit, charr, yv, trans, startv, endv, logZ,
                                   (float*)d_out);
}

// Round 10
// 507.570 us; speedup vs baseline: 1.4289x; 1.0282x over previous
//
#include <hip/hip_runtime.h>
#include <math.h>

#define BB 32
#define TT 512
#define DW 128
#define DC 64
#define DD 192
#define HH 128
#define G4 512
#define LL 32

typedef __fp16 h2_t __attribute__((ext_vector_type(2)));

__device__ __forceinline__ h2_t bch2(unsigned int x) { return __builtin_bit_cast(h2_t, x); }

// quad_perm lane-xor via DPP (VALU, not LDS)
__device__ __forceinline__ float qxor1(float x) {
    return __int_as_float(__builtin_amdgcn_update_dpp(0, __float_as_int(x), 0xB1, 0xF, 0xF, true));
}
__device__ __forceinline__ float qxor2(float x) {
    return __int_as_float(__builtin_amdgcn_update_dpp(0, __float_as_int(x), 0x4E, 0xF, 0xF, true));
}
// quad_perm broadcast of lane q (within each quad)
__device__ __forceinline__ float qbcast(float x, int ctrl_imm) {
    switch (ctrl_imm) {
        case 0: return __int_as_float(__builtin_amdgcn_update_dpp(0, __float_as_int(x), 0x00, 0xF, 0xF, true));
        case 1: return __int_as_float(__builtin_amdgcn_update_dpp(0, __float_as_int(x), 0x55, 0xF, 0xF, true));
        case 2: return __int_as_float(__builtin_amdgcn_update_dpp(0, __float_as_int(x), 0xAA, 0xF, 0xF, true));
        default:return __int_as_float(__builtin_amdgcn_update_dpp(0, __float_as_int(x), 0xFF, 0xF, 0xF, true));
    }
}

// ---------------------------------------------------------------------------
// K1: fused embedding-gather + input projection GEMM, f16 dot2.
// v4: SINGLE-STAGE — A-tile (128 tok x 192) and B-tile (256 cols x 192)
// both staged to LDS once (147 KB), ONE barrier, then all 96 k-pair steps
// of compute run barrier-free. Replaces the 48-barrier chunked version.
// Grid: (128 ntiles, 4) -> ctile = dir*2 + colhalf. 512 threads.
// ---------------------------------------------------------------------------
__global__ __launch_bounds__(512) void k_inproj(
    const int* __restrict__ word, const int* __restrict__ charr,
    const float* __restrict__ wemb, const float* __restrict__ cemb,
    const float* __restrict__ Wf, const float* __restrict__ bf,
    const float* __restrict__ Wb, const float* __restrict__ bb,
    float* __restrict__ xpf, float* __restrict__ xpb)
{
    __shared__ __align__(16) h2_t As2[96][132];   // [k-pair][token-row]
    __shared__ __align__(16) h2_t Bs2[96][260];   // [k-pair][gate-col]
    const int tid = threadIdx.x;
    const int ntile = blockIdx.x;           // 0..127
    const int ctile = blockIdx.y;           // 0..3
    const int dir = ctile >> 1;
    const float* W = dir ? Wb : Wf;
    const float* bias = dir ? bb : bf;
    float* xp = dir ? xpb : xpf;
    const int colbase = (ctile & 1) * 256;  // within the 512 gate-cols

    // ---- stage A: 128 tokens x 192 floats -> h2 (4 threads per row) ----
    {
        const int lrow = tid >> 2;          // 0..127
        const int lq   = tid & 3;
        const int nA   = ntile * 128 + lrow;
        const int wi   = word[nA];
        const int ci   = charr[nA];
#pragma unroll
        for (int kc = 0; kc < 12; ++kc) {
            const int k0 = kc * 16 + lq * 4;
            float4 av;
            if (k0 < DW) av = *(const float4*)(wemb + (size_t)wi * DW + k0);
            else         av = *(const float4*)(cemb + (size_t)ci * DC + (k0 - DW));
            const int kp = k0 >> 1;
            As2[kp    ][lrow] = __builtin_amdgcn_cvt_pkrtz(av.x, av.y);
            As2[kp + 1][lrow] = __builtin_amdgcn_cvt_pkrtz(av.z, av.w);
        }
    }
    // ---- stage B: 256 gate-cols x 192 floats -> h2 (2 threads per col) ----
    {
        const int lcol = tid >> 1;          // 0..255
        const int lh   = tid & 1;
        const int g    = colbase + lcol;
#pragma unroll
        for (int kc = 0; kc < 24; ++kc) {
            const int k0 = kc * 8 + lh * 4;
            const float4 bv = *(const float4*)(W + (size_t)g * DD + k0);
            const int kp = k0 >> 1;
            Bs2[kp    ][lcol] = __builtin_amdgcn_cvt_pkrtz(bv.x, bv.y);
            Bs2[kp + 1][lcol] = __builtin_amdgcn_cvt_pkrtz(bv.z, bv.w);
        }
    }
    __syncthreads();

    // ---- compute: 8x8 outputs per thread over 96 k-pairs, no barriers ----
    const int tr = tid >> 5;    // 0..15  (token block)
    const int tc = tid & 31;    // 0..31  (col block)
    float acc[8][8];
#pragma unroll
    for (int i = 0; i < 8; ++i)
#pragma unroll
        for (int j = 0; j < 8; ++j) acc[i][j] = 0.f;

    for (int kc = 0; kc < 24; ++kc) {
#pragma unroll
        for (int kq = 0; kq < 4; ++kq) {
            const int kp = kc * 4 + kq;
            h2_t __attribute__((aligned(16))) a2[8], b2[8];
            *(uint4*)&a2[0] = *(const uint4*)&As2[kp][tr * 8];
            *(uint4*)&a2[4] = *(const uint4*)&As2[kp][tr * 8 + 4];
            *(uint4*)&b2[0] = *(const uint4*)&Bs2[kp][tc * 8];
            *(uint4*)&b2[4] = *(const uint4*)&Bs2[kp][tc * 8 + 4];
#pragma unroll
            for (int i = 0; i < 8; ++i)
#pragma unroll
                for (int j = 0; j < 8; ++j)
                    acc[i][j] = __builtin_amdgcn_fdot2(a2[i], b2[j], acc[i][j], false);
        }
    }
#pragma unroll
    for (int i = 0; i < 8; ++i) {
        const int n  = ntile * 128 + tr * 8 + i;
        const int b_ = n >> 9, t_ = n & 511;
        float* dst = xp + ((size_t)(t_ * BB + b_)) * G4 + colbase + tc * 8;
#pragma unroll
        for (int j = 0; j < 8; ++j) dst[j] = acc[i][j] + bias[colbase + tc * 8 + j];
    }
}

// ---------------------------------------------------------------------------
// K2: LSTM scan (R7 verbatim — best measured: 270 us). 64 blocks, 512 thr.
// Thread (u=tid>>2, ks=tid&3), f16 dot2, weights resident (64 VGPRs).
// ---------------------------------------------------------------------------
__global__ __launch_bounds__(512)
__attribute__((amdgpu_waves_per_eu(2, 2)))
void k_lstm(
    const float* __restrict__ xpf, const float* __restrict__ xpb,
    const float* __restrict__ Whf, const float* __restrict__ Whb,
    float* __restrict__ hf, float* __restrict__ hb)
{
    // [buf][ks*40 + j] f16 units; per-ks block = 80 B -> conflict-free.
    __shared__ __align__(16) __fp16 hsd[2][160];
    const int tid = threadIdx.x;
    const int dir = blockIdx.x >> 5;
    const int b_  = blockIdx.x & 31;
    const float* xp = dir ? xpb : xpf;
    const float* Wh = dir ? Whb : Whf;
    float* hout = dir ? hb : hf;
    const int ks = tid & 3;          // k-quarter (32 wide) == owned gate id
    const int u  = tid >> 2;         // hidden unit 0..127

    // W_hh[g*128+u][ks*32 .. +31] for g=0..3 as packed half2: 4x16 = 64 VGPRs
    h2_t w2[4][16];
#pragma unroll
    for (int g = 0; g < 4; ++g) {
        const float2* wp = (const float2*)(Wh + (size_t)(g * 128 + u) * HH + ks * 32);
#pragma unroll
        for (int j = 0; j < 16; ++j)
            w2[g][j] = __builtin_amdgcn_cvt_pkrtz(wp[j].x, wp[j].y);
    }

    const float mk0 = (ks == 0) ? 1.f : 0.f;
    const float mk1 = (ks == 1) ? 1.f : 0.f;
    const float mk2 = (ks == 2) ? 1.f : 0.f;
    const float mk3 = (ks == 3) ? 1.f : 0.f;
    const bool istanh = (ks == 2);
    const float GS  = istanh ? 2.f : -1.f;
    const float GC0 = istanh ? 1.f : 0.f;
    const float GC1 = istanh ? -2.f : 1.f;
    const bool ks1 = (ks & 1) != 0;
    const bool ks2 = (ks & 2) != 0;

    if (tid < 80) ((unsigned int*)&hsd[0][0])[tid] = 0u;   // zero buffer 0
    float c = 0.f;
    const int t0 = dir ? (TT - 1) : 0;
    const int tstep = dir ? -1 : 1;
    const int xstride = tstep * BB * G4;
    const int hstride = tstep * BB * HH;
    const float* xqp = xp + ((long long)t0 * BB + b_) * G4 + ks * 128 + u;
    float*       hop = hout + ((long long)t0 * BB + b_) * HH + u;
    float xq = *xqp;
    __syncthreads();

    for (int s = 0; s < TT; ++s) {
        const int rb = s & 1;
        float p0 = mk0 * xq, p1 = mk1 * xq, p2 = mk2 * xq, p3 = mk3 * xq;
        // prefetch next xp now (one-past-end lands in adjacent ws buffer)
        xqp += xstride;
        xq = *xqp;
#pragma unroll
        for (int q = 0; q < 4; ++q) {
            const uint4 hv = *(const uint4*)&hsd[rb][ks * 40 + q * 8];
            const h2_t ha  = bch2(hv.x);
            const h2_t hbv = bch2(hv.y);
            const h2_t hc  = bch2(hv.z);
            const h2_t hd  = bch2(hv.w);
            p0 = __builtin_amdgcn_fdot2(ha,  w2[0][q*4+0], p0, false);
            p0 = __builtin_amdgcn_fdot2(hbv, w2[0][q*4+1], p0, false);
            p0 = __builtin_amdgcn_fdot2(hc,  w2[0][q*4+2], p0, false);
            p0 = __builtin_amdgcn_fdot2(hd,  w2[0][q*4+3], p0, false);
            p1 = __builtin_amdgcn_fdot2(ha,  w2[1][q*4+0], p1, false);
            p1 = __builtin_amdgcn_fdot2(hbv, w2[1][q*4+1], p1, false);
            p1 = __builtin_amdgcn_fdot2(hc,  w2[1][q*4+2], p1, false);
            p1 = __builtin_amdgcn_fdot2(hd,  w2[1][q*4+3], p1, false);
            p2 = __builtin_amdgcn_fdot2(ha,  w2[2][q*4+0], p2, false);
            p2 = __builtin_amdgcn_fdot2(hbv, w2[2][q*4+1], p2, false);
            p2 = __builtin_amdgcn_fdot2(hc,  w2[2][q*4+2], p2, false);
            p2 = __builtin_amdgcn_fdot2(hd,  w2[2][q*4+3], p2, false);
            p3 = __builtin_amdgcn_fdot2(ha,  w2[3][q*4+0], p3, false);
            p3 = __builtin_amdgcn_fdot2(hbv, w2[3][q*4+1], p3, false);
            p3 = __builtin_amdgcn_fdot2(hc,  w2[3][q*4+2], p3, false);
            p3 = __builtin_amdgcn_fdot2(hd,  w2[3][q*4+3], p3, false);
        }
        // quad butterfly: every lane ends with ALL four complete gate sums
        p0 += qxor1(p0); p0 += qxor2(p0);
        p1 += qxor1(p1); p1 += qxor2(p1);
        p2 += qxor1(p2); p2 += qxor2(p2);
        p3 += qxor1(p3); p3 += qxor2(p3);
        // lane ks computes only its gate's nonlinearity, quad_perm regather
        const float pa   = ks1 ? p1 : p0;
        const float pb   = ks1 ? p3 : p2;
        const float psel = ks2 ? pb : pa;
        const float val  = GC0 + GC1 * __builtin_amdgcn_rcpf(1.f + __expf(GS * psel));
        const float gi = qbcast(val, 0);
        const float gf = qbcast(val, 1);
        const float gg = qbcast(val, 2);
        const float go = qbcast(val, 3);
        c = gf * c + gi * gg;
        const float tc = 1.f - 2.f * __builtin_amdgcn_rcpf(1.f + __expf(2.f * c));
        const float hv = go * tc;
        if (ks == 0) {
            hsd[rb ^ 1][(u >> 5) * 40 + (u & 31)] = (__fp16)hv;
            *hop = hv;
        }
        hop += hstride;
        // raw barrier, NO memory clobber: order only LDS (lgkm), leave
        // global store + prefetch load in flight.
        __builtin_amdgcn_sched_barrier(0);
        asm volatile("s_waitcnt lgkmcnt(0)");
        __builtin_amdgcn_s_barrier();
        __builtin_amdgcn_sched_barrier(0);
    }
}

// ---------------------------------------------------------------------------
// K3: emit[t][b][l] = (concat(hf,hb)[t][b][:] . W_out[l,:] + b_out[l]) * mask
// ---------------------------------------------------------------------------
__global__ __launch_bounds__(1024) void k_emit(
    const float* __restrict__ hf, const float* __restrict__ hb,
    const float* __restrict__ Wout, const float* __restrict__ bout,
    const int* __restrict__ charr, float* __restrict__ emit)
{
    __shared__ __align__(16) float hsm[BB * 256];
    __shared__ __align__(16) float wsm[LL * 260];
    const int t = blockIdx.x;
    const int tid = threadIdx.x;
    for (int idx = tid; idx < BB * 256; idx += 1024) {
        const int b_ = idx >> 8, u = idx & 255;
        hsm[idx] = (u < HH) ? hf[((size_t)t * BB + b_) * HH + u]
                            : hb[((size_t)t * BB + b_) * HH + (u - HH)];
    }
    for (int idx = tid; idx < LL * 256; idx += 1024) {
        const int l = idx >> 8, u = idx & 255;
        wsm[l * 260 + u] = Wout[idx];
    }
    __syncthreads();
    const int b_ = tid >> 5, l = tid & 31;
    float acc = bout[l];
#pragma unroll 8
    for (int q = 0; q < 64; ++q) {
        const float4 h4 = *(const float4*)&hsm[b_ * 256 + q * 4];
        const float4 w4 = *(const float4*)&wsm[l * 260 + q * 4];
        acc += h4.x * w4.x + h4.y * w4.y + h4.z * w4.z + h4.w * w4.w;
    }
    const float m = (charr[b_ * TT + t] > 0) ? 1.f : 0.f;
    emit[((size_t)t * BB + b_) * LL + l] = acc * m;
}

// ---------------------------------------------------------------------------
// K4: CRF forward v3 — linear-space + readlane matvec (no ds_bpermute).
// ---------------------------------------------------------------------------
__global__ __launch_bounds__(64) void k_crf(
    const float* __restrict__ emit, const int* __restrict__ charr,
    const float* __restrict__ trans, const float* __restrict__ startv,
    const float* __restrict__ endv, float* __restrict__ logZ)
{
    const int tid = threadIdx.x;             // lanes 32..63 mirror lanes 0..31
    const int b_ = blockIdx.x;
    const int j = tid & 31;
    float et[32];
#pragma unroll
    for (int i = 0; i < 32; ++i) et[i] = __expf(trans[i * LL + j]);

    const float a0 = startv[j] + emit[(size_t)b_ * LL + j];
    float M = a0;
    M = fmaxf(M, __shfl_xor(M, 16));
    M = fmaxf(M, __shfl_xor(M, 8));
    M = fmaxf(M, __shfl_xor(M, 4));
    M = fmaxf(M, __shfl_xor(M, 2));
    M = fmaxf(M, __shfl_xor(M, 1));
    float A = __expf(a0 - M);
    float logsc = M;

    float e_nx = emit[((size_t)1 * BB + b_) * LL + j];
    int   m_nx = charr[b_ * TT + 1];

    for (int t = 1; t < TT; ++t) {
        const float ee = __expf(e_nx);       // off critical chain (prefetched)
        const int m_cur = m_nx;
        if (t + 1 < TT) {
            e_nx = emit[((size_t)(t + 1) * BB + b_) * LL + j];
            m_nx = charr[b_ * TT + t + 1];
        }
        float s0 = 0.f, s1 = 0.f, s2 = 0.f, s3 = 0.f;
#pragma unroll
        for (int i = 0; i < 32; i += 4) {
            s0 = fmaf(__int_as_float(__builtin_amdgcn_readlane(__float_as_int(A), i    )), et[i    ], s0);
            s1 = fmaf(__int_as_float(__builtin_amdgcn_readlane(__float_as_int(A), i + 1)), et[i + 1], s1);
            s2 = fmaf(__int_as_float(__builtin_amdgcn_readlane(__float_as_int(A), i + 2)), et[i + 2], s2);
            s3 = fmaf(__int_as_float(__builtin_amdgcn_readlane(__float_as_int(A), i + 3)), et[i + 3], s3);
        }
        const float Anew = ((s0 + s1) + (s2 + s3)) * ee;
        A = (m_cur > 0) ? Anew : A;
        if ((t & 7) == 0) {                  // renorm every 8 steps
            float S = A;
            S = fmaxf(S, __shfl_xor(S, 16));
            S = fmaxf(S, __shfl_xor(S, 8));
            S = fmaxf(S, __shfl_xor(S, 4));
            S = fmaxf(S, __shfl_xor(S, 2));
            S = fmaxf(S, __shfl_xor(S, 1));
            A *= __builtin_amdgcn_rcpf(S);
            logsc += __logf(S);
        }
    }
    // finalize: alpha_j = log(A_j) + logsc; logZ = LSE_j(alpha_j + end_j)
    const float z = __logf(A) + logsc + endv[j];
    float Mz = z;
    Mz = fmaxf(Mz, __shfl_xor(Mz, 16));
    Mz = fmaxf(Mz, __shfl_xor(Mz, 8));
    Mz = fmaxf(Mz, __shfl_xor(Mz, 4));
    Mz = fmaxf(Mz, __shfl_xor(Mz, 2));
    Mz = fmaxf(Mz, __shfl_xor(Mz, 1));
    float sz = __expf(z - Mz);
    sz += __shfl_xor(sz, 16);
    sz += __shfl_xor(sz, 8);
    sz += __shfl_xor(sz, 4);
    sz += __shfl_xor(sz, 2);
    sz += __shfl_xor(sz, 1);
    if (tid == 0) logZ[b_] = Mz + __logf(sz);
}

// ---------------------------------------------------------------------------
// K5: gold path score + final output scalar.
// ---------------------------------------------------------------------------
__global__ __launch_bounds__(1024) void k_gold(
    const float* __restrict__ emit, const int* __restrict__ charr,
    const int* __restrict__ y, const float* __restrict__ trans,
    const float* __restrict__ startv, const float* __restrict__ endv,
    const float* __restrict__ logZ, float* __restrict__ out)
{
    __shared__ float red[BB];
    const int tid = threadIdx.x;
    const int b_ = tid >> 5, l = tid & 31;
    float sc = 0.f;
    int ms = 0;
    for (int t = l; t < TT; t += 32) {
        const int yv = y[b_ * TT + t];
        const int m = (charr[b_ * TT + t] > 0);
        if (m) { sc += emit[((size_t)t * BB + b_) * LL + yv]; ms++; }
        if (t + 1 < TT) {
            const int mn = (charr[b_ * TT + t + 1] > 0);
            if (mn) sc += trans[yv * LL + y[b_ * TT + t + 1]];
        }
    }
#pragma unroll
    for (int o = 16; o; o >>= 1) {
        sc += __shfl_xor(sc, o);
        ms += __shfl_xor(ms, o);
    }
    if (l == 0) {
        int last = ms - 1;
        if (last < 0) last = 0;
        const float gold = startv[y[b_ * TT]] + sc + endv[y[b_ * TT + last]];
        red[b_] = logZ[b_] - gold;
    }
    __syncthreads();
    if (tid == 0) {
        float tot = 0.f;
#pragma unroll
        for (int i = 0; i < BB; ++i) tot += red[i];
        out[0] = tot;
    }
}

extern "C" void kernel_launch(void* const* d_in, const int* in_sizes, int n_in,
                              void* d_out, int out_size, void* d_ws, size_t ws_size,
                              hipStream_t stream) {
    (void)in_sizes; (void)n_in; (void)out_size; (void)ws_size;
    const int*   word  = (const int*)d_in[0];
    const int*   charr = (const int*)d_in[1];
    const int*   yv    = (const int*)d_in[2];
    const float* wemb  = (const float*)d_in[3];
    const float* cemb  = (const float*)d_in[4];
    const float* Wihf  = (const float*)d_in[5];
    const float* Whhf  = (const float*)d_in[6];
    const float* bf    = (const float*)d_in[7];
    const float* Wihb  = (const float*)d_in[8];
    const float* Whhb  = (const float*)d_in[9];
    const float* bb    = (const float*)d_in[10];
    const float* Wout  = (const float*)d_in[11];
    const float* bout  = (const float*)d_in[12];
    const float* trans = (const float*)d_in[13];
    const float* startv= (const float*)d_in[14];
    const float* endv  = (const float*)d_in[15];

    float* ws   = (float*)d_ws;
    float* xpf  = ws;                       // [T][B][512]
    float* xpb  = xpf + (size_t)TT * BB * G4;
    float* hf   = xpb + (size_t)TT * BB * G4;   // [T][B][128]
    float* hb   = hf + (size_t)TT * BB * HH;
    float* emit = hb + (size_t)TT * BB * HH;    // [T][B][32]
    float* logZ = emit + (size_t)TT * BB * LL;  // [32]

    k_inproj<<<dim3(128, 4), 512, 0, stream>>>(word, charr, wemb, cemb,
                                               Wihf, bf, Wihb, bb, xpf, xpb);
    k_lstm<<<64, 512, 0, stream>>>(xpf, xpb, Whhf, Whhb, hf, hb);
    k_emit<<<TT, 1024, 0, stream>>>(hf, hb, Wout, bout, charr, emit);
    k_crf<<<32, 64, 0, stream>>>(emit, charr, trans, startv, endv, logZ);
    k_gold<<<1, 1024, 0, stream>>>(emit, charr, yv, trans, startv, endv, logZ,
                                   (float*)d_out);
}

// Round 11
// 435.818 us; speedup vs baseline: 1.6641x; 1.1646x over previous
//
#include <hip/hip_runtime.h>
#include <math.h>

#define BB 32
#define TT 512
#define DW 128
#define DC 64
#define DD 192
#define HH 128
#define G4 512
#define LL 32

typedef __fp16 h2_t __attribute__((ext_vector_type(2)));

__device__ __forceinline__ h2_t bch2(unsigned int x) { return __builtin_bit_cast(h2_t, x); }

// quad_perm lane-xor via DPP (VALU, not LDS)
__device__ __forceinline__ float qxor1(float x) {
    return __int_as_float(__builtin_amdgcn_update_dpp(0, __float_as_int(x), 0xB1, 0xF, 0xF, true));
}
__device__ __forceinline__ float qxor2(float x) {
    return __int_as_float(__builtin_amdgcn_update_dpp(0, __float_as_int(x), 0x4E, 0xF, 0xF, true));
}
// quad_perm broadcast of lane q (within each quad)
__device__ __forceinline__ float qbcast(float x, int ctrl_imm) {
    switch (ctrl_imm) {
        case 0: return __int_as_float(__builtin_amdgcn_update_dpp(0, __float_as_int(x), 0x00, 0xF, 0xF, true));
        case 1: return __int_as_float(__builtin_amdgcn_update_dpp(0, __float_as_int(x), 0x55, 0xF, 0xF, true));
        case 2: return __int_as_float(__builtin_amdgcn_update_dpp(0, __float_as_int(x), 0xAA, 0xF, 0xF, true));
        default:return __int_as_float(__builtin_amdgcn_update_dpp(0, __float_as_int(x), 0xFF, 0xF, 0xF, true));
    }
}

// ---------------------------------------------------------------------------
// K1: fused embedding-gather + input projection GEMM, f16 dot2, single-stage
// (R10 structure). Also zeroes out[0] (needed by k_crf's atomicAdd).
// ---------------------------------------------------------------------------
__global__ __launch_bounds__(512) void k_inproj(
    const int* __restrict__ word, const int* __restrict__ charr,
    const float* __restrict__ wemb, const float* __restrict__ cemb,
    const float* __restrict__ Wf, const float* __restrict__ bf,
    const float* __restrict__ Wb, const float* __restrict__ bb,
    float* __restrict__ xpf, float* __restrict__ xpb,
    float* __restrict__ out)
{
    __shared__ __align__(16) h2_t As2[96][132];   // [k-pair][token-row]
    __shared__ __align__(16) h2_t Bs2[96][260];   // [k-pair][gate-col]
    const int tid = threadIdx.x;
    const int ntile = blockIdx.x;           // 0..127
    const int ctile = blockIdx.y;           // 0..3
    if (ntile == 0 && ctile == 0 && tid == 0) out[0] = 0.f;
    const int dir = ctile >> 1;
    const float* W = dir ? Wb : Wf;
    const float* bias = dir ? bb : bf;
    float* xp = dir ? xpb : xpf;
    const int colbase = (ctile & 1) * 256;  // within the 512 gate-cols

    // ---- stage A: 128 tokens x 192 floats -> h2 (4 threads per row) ----
    {
        const int lrow = tid >> 2;          // 0..127
        const int lq   = tid & 3;
        const int nA   = ntile * 128 + lrow;
        const int wi   = word[nA];
        const int ci   = charr[nA];
#pragma unroll
        for (int kc = 0; kc < 12; ++kc) {
            const int k0 = kc * 16 + lq * 4;
            float4 av;
            if (k0 < DW) av = *(const float4*)(wemb + (size_t)wi * DW + k0);
            else         av = *(const float4*)(cemb + (size_t)ci * DC + (k0 - DW));
            const int kp = k0 >> 1;
            As2[kp    ][lrow] = __builtin_amdgcn_cvt_pkrtz(av.x, av.y);
            As2[kp + 1][lrow] = __builtin_amdgcn_cvt_pkrtz(av.z, av.w);
        }
    }
    // ---- stage B: 256 gate-cols x 192 floats -> h2 (2 threads per col) ----
    {
        const int lcol = tid >> 1;          // 0..255
        const int lh   = tid & 1;
        const int g    = colbase + lcol;
#pragma unroll
        for (int kc = 0; kc < 24; ++kc) {
            const int k0 = kc * 8 + lh * 4;
            const float4 bv = *(const float4*)(W + (size_t)g * DD + k0);
            const int kp = k0 >> 1;
            Bs2[kp    ][lcol] = __builtin_amdgcn_cvt_pkrtz(bv.x, bv.y);
            Bs2[kp + 1][lcol] = __builtin_amdgcn_cvt_pkrtz(bv.z, bv.w);
        }
    }
    __syncthreads();

    // ---- compute: 8x8 outputs per thread over 96 k-pairs, no barriers ----
    const int tr = tid >> 5;    // 0..15  (token block)
    const int tc = tid & 31;    // 0..31  (col block)
    float acc[8][8];
#pragma unroll
    for (int i = 0; i < 8; ++i)
#pragma unroll
        for (int j = 0; j < 8; ++j) acc[i][j] = 0.f;

    for (int kc = 0; kc < 24; ++kc) {
#pragma unroll
        for (int kq = 0; kq < 4; ++kq) {
            const int kp = kc * 4 + kq;
            h2_t __attribute__((aligned(16))) a2[8], b2[8];
            *(uint4*)&a2[0] = *(const uint4*)&As2[kp][tr * 8];
            *(uint4*)&a2[4] = *(const uint4*)&As2[kp][tr * 8 + 4];
            *(uint4*)&b2[0] = *(const uint4*)&Bs2[kp][tc * 8];
            *(uint4*)&b2[4] = *(const uint4*)&Bs2[kp][tc * 8 + 4];
#pragma unroll
            for (int i = 0; i < 8; ++i)
#pragma unroll
                for (int j = 0; j < 8; ++j)
                    acc[i][j] = __builtin_amdgcn_fdot2(a2[i], b2[j], acc[i][j], false);
        }
    }
#pragma unroll
    for (int i = 0; i < 8; ++i) {
        const int n  = ntile * 128 + tr * 8 + i;
        const int b_ = n >> 9, t_ = n & 511;
        float* dst = xp + ((size_t)(t_ * BB + b_)) * G4 + colbase + tc * 8;
#pragma unroll
        for (int j = 0; j < 8; ++j) dst[j] = acc[i][j] + bias[colbase + tc * 8 + j];
    }
}

// ---------------------------------------------------------------------------
// K2: LSTM scan (R7 structure — best measured). 64 blocks, 512 threads.
// Only change: hout stored as __fp16 (halves write traffic).
// ---------------------------------------------------------------------------
__global__ __launch_bounds__(512)
__attribute__((amdgpu_waves_per_eu(2, 2)))
void k_lstm(
    const float* __restrict__ xpf, const float* __restrict__ xpb,
    const float* __restrict__ Whf, const float* __restrict__ Whb,
    __fp16* __restrict__ hf, __fp16* __restrict__ hb)
{
    // [buf][ks*40 + j] f16 units; per-ks block = 80 B -> conflict-free.
    __shared__ __align__(16) __fp16 hsd[2][160];
    const int tid = threadIdx.x;
    const int dir = blockIdx.x >> 5;
    const int b_  = blockIdx.x & 31;
    const float* xp = dir ? xpb : xpf;
    const float* Wh = dir ? Whb : Whf;
    __fp16* hout = dir ? hb : hf;
    const int ks = tid & 3;          // k-quarter (32 wide) == owned gate id
    const int u  = tid >> 2;         // hidden unit 0..127

    // W_hh[g*128+u][ks*32 .. +31] for g=0..3 as packed half2: 4x16 = 64 VGPRs
    h2_t w2[4][16];
#pragma unroll
    for (int g = 0; g < 4; ++g) {
        const float2* wp = (const float2*)(Wh + (size_t)(g * 128 + u) * HH + ks * 32);
#pragma unroll
        for (int j = 0; j < 16; ++j)
            w2[g][j] = __builtin_amdgcn_cvt_pkrtz(wp[j].x, wp[j].y);
    }

    const float mk0 = (ks == 0) ? 1.f : 0.f;
    const float mk1 = (ks == 1) ? 1.f : 0.f;
    const float mk2 = (ks == 2) ? 1.f : 0.f;
    const float mk3 = (ks == 3) ? 1.f : 0.f;
    const bool istanh = (ks == 2);
    const float GS  = istanh ? 2.f : -1.f;
    const float GC0 = istanh ? 1.f : 0.f;
    const float GC1 = istanh ? -2.f : 1.f;
    const bool ks1 = (ks & 1) != 0;
    const bool ks2 = (ks & 2) != 0;

    if (tid < 80) ((unsigned int*)&hsd[0][0])[tid] = 0u;   // zero buffer 0
    float c = 0.f;
    const int t0 = dir ? (TT - 1) : 0;
    const int tstep = dir ? -1 : 1;
    const int xstride = tstep * BB * G4;
    const int hstride = tstep * BB * HH;
    const float* xqp = xp + ((long long)t0 * BB + b_) * G4 + ks * 128 + u;
    __fp16*      hop = hout + ((long long)t0 * BB + b_) * HH + u;
    float xq = *xqp;
    __syncthreads();

    for (int s = 0; s < TT; ++s) {
        const int rb = s & 1;
        float p0 = mk0 * xq, p1 = mk1 * xq, p2 = mk2 * xq, p3 = mk3 * xq;
        // prefetch next xp now (one-past-end lands in adjacent ws buffer)
        xqp += xstride;
        xq = *xqp;
#pragma unroll
        for (int q = 0; q < 4; ++q) {
            const uint4 hv = *(const uint4*)&hsd[rb][ks * 40 + q * 8];
            const h2_t ha  = bch2(hv.x);
            const h2_t hbv = bch2(hv.y);
            const h2_t hc  = bch2(hv.z);
            const h2_t hd  = bch2(hv.w);
            p0 = __builtin_amdgcn_fdot2(ha,  w2[0][q*4+0], p0, false);
            p0 = __builtin_amdgcn_fdot2(hbv, w2[0][q*4+1], p0, false);
            p0 = __builtin_amdgcn_fdot2(hc,  w2[0][q*4+2], p0, false);
            p0 = __builtin_amdgcn_fdot2(hd,  w2[0][q*4+3], p0, false);
            p1 = __builtin_amdgcn_fdot2(ha,  w2[1][q*4+0], p1, false);
            p1 = __builtin_amdgcn_fdot2(hbv, w2[1][q*4+1], p1, false);
            p1 = __builtin_amdgcn_fdot2(hc,  w2[1][q*4+2], p1, false);
            p1 = __builtin_amdgcn_fdot2(hd,  w2[1][q*4+3], p1, false);
            p2 = __builtin_amdgcn_fdot2(ha,  w2[2][q*4+0], p2, false);
            p2 = __builtin_amdgcn_fdot2(hbv, w2[2][q*4+1], p2, false);
            p2 = __builtin_amdgcn_fdot2(hc,  w2[2][q*4+2], p2, false);
            p2 = __builtin_amdgcn_fdot2(hd,  w2[2][q*4+3], p2, false);
            p3 = __builtin_amdgcn_fdot2(ha,  w2[3][q*4+0], p3, false);
            p3 = __builtin_amdgcn_fdot2(hbv, w2[3][q*4+1], p3, false);
            p3 = __builtin_amdgcn_fdot2(hc,  w2[3][q*4+2], p3, false);
            p3 = __builtin_amdgcn_fdot2(hd,  w2[3][q*4+3], p3, false);
        }
        // quad butterfly: every lane ends with ALL four complete gate sums
        p0 += qxor1(p0); p0 += qxor2(p0);
        p1 += qxor1(p1); p1 += qxor2(p1);
        p2 += qxor1(p2); p2 += qxor2(p2);
        p3 += qxor1(p3); p3 += qxor2(p3);
        // lane ks computes only its gate's nonlinearity, quad_perm regather
        const float pa   = ks1 ? p1 : p0;
        const float pb   = ks1 ? p3 : p2;
        const float psel = ks2 ? pb : pa;
        const float val  = GC0 + GC1 * __builtin_amdgcn_rcpf(1.f + __expf(GS * psel));
        const float gi = qbcast(val, 0);
        const float gf = qbcast(val, 1);
        const float gg = qbcast(val, 2);
        const float go = qbcast(val, 3);
        c = gf * c + gi * gg;
        const float tc = 1.f - 2.f * __builtin_amdgcn_rcpf(1.f + __expf(2.f * c));
        const float hv = go * tc;
        const __fp16 hv16 = (__fp16)hv;
        if (ks == 0) {
            hsd[rb ^ 1][(u >> 5) * 40 + (u & 31)] = hv16;
            *hop = hv16;
        }
        hop += hstride;
        // raw barrier, NO memory clobber: order only LDS (lgkm), leave
        // global store + prefetch load in flight.
        __builtin_amdgcn_sched_barrier(0);
        asm volatile("s_waitcnt lgkmcnt(0)");
        __builtin_amdgcn_s_barrier();
        __builtin_amdgcn_sched_barrier(0);
    }
}

// ---------------------------------------------------------------------------
// K3: emit[t][b][l] = (concat(hf,hb)[t][b][:] . W_out[l,:] + b_out[l]) * mask
// v2: f16 staging + fdot2; wsm2 pitch 130 dwords -> 2-way bank alias (free).
// ---------------------------------------------------------------------------
__global__ __launch_bounds__(1024) void k_emit(
    const __fp16* __restrict__ hf, const __fp16* __restrict__ hb,
    const float* __restrict__ Wout, const float* __restrict__ bout,
    const int* __restrict__ charr, float* __restrict__ emit)
{
    __shared__ __align__(16) unsigned int hsm2[BB * 132];   // [b][132] h2-pitch
    __shared__ __align__(16) unsigned int wsm2[LL * 130];   // [l][130] h2-pitch
    const int t = blockIdx.x;
    const int tid = threadIdx.x;
    // stage h: 32 b x 128 h2 (64 from hf, 64 from hb)
    const unsigned int* hfu = (const unsigned int*)hf;
    const unsigned int* hbu = (const unsigned int*)hb;
    for (int idx = tid; idx < BB * 128; idx += 1024) {
        const int b_ = idx >> 7, k = idx & 127;
        const unsigned int v = (k < 64)
            ? hfu[((size_t)t * BB + b_) * 64 + k]
            : hbu[((size_t)t * BB + b_) * 64 + (k - 64)];
        hsm2[b_ * 132 + k] = v;
    }
    // stage Wout: 32 l x 128 h2 (cvt f32->f16)
    for (int idx = tid; idx < LL * 128; idx += 1024) {
        const int l = idx >> 7, kp = idx & 127;
        const float2 wv = ((const float2*)Wout)[l * 128 + kp];
        wsm2[l * 130 + kp] = __builtin_bit_cast(unsigned int,
            __builtin_amdgcn_cvt_pkrtz(wv.x, wv.y));
    }
    __syncthreads();
    const int b_ = tid >> 5, l = tid & 31;
    float acc = bout[l];
#pragma unroll 8
    for (int q = 0; q < 32; ++q) {
        const uint4 h4 = *(const uint4*)&hsm2[b_ * 132 + q * 4];
        const uint2 wa = *(const uint2*)&wsm2[l * 130 + q * 4];
        const uint2 wb = *(const uint2*)&wsm2[l * 130 + q * 4 + 2];
        acc = __builtin_amdgcn_fdot2(bch2(h4.x), bch2(wa.x), acc, false);
        acc = __builtin_amdgcn_fdot2(bch2(h4.y), bch2(wa.y), acc, false);
        acc = __builtin_amdgcn_fdot2(bch2(h4.z), bch2(wb.x), acc, false);
        acc = __builtin_amdgcn_fdot2(bch2(h4.w), bch2(wb.y), acc, false);
    }
    const float m = (charr[b_ * TT + t] > 0) ? 1.f : 0.f;
    emit[((size_t)t * BB + b_) * LL + l] = acc * m;
}

// ---------------------------------------------------------------------------
// K4: CRF forward + gold score, fused. 32 blocks x 64 threads.
// Linear-space alpha recurrence with readlane matvec; gold computed
// lane-parallel first; result accumulated into out[0] via atomicAdd.
// ---------------------------------------------------------------------------
__global__ __launch_bounds__(64) void k_crf(
    const float* __restrict__ emit, const int* __restrict__ charr,
    const int* __restrict__ y, const float* __restrict__ trans,
    const float* __restrict__ startv, const float* __restrict__ endv,
    float* __restrict__ out)
{
    const int tid = threadIdx.x;             // lanes 32..63 mirror lanes 0..31
    const int b_ = blockIdx.x;
    const int j = tid & 31;

    // ---- gold path score: lane-parallel over t (stride 64) ----
    float sc = 0.f;
    int ms = 0;
    for (int t = tid; t < TT; t += 64) {
        const int yv = y[b_ * TT + t];
        const int m = (charr[b_ * TT + t] > 0);
        if (m) { sc += emit[((size_t)t * BB + b_) * LL + yv]; ms++; }
        if (t + 1 < TT) {
            const int mn = (charr[b_ * TT + t + 1] > 0);
            if (mn) sc += trans[yv * LL + y[b_ * TT + t + 1]];
        }
    }
#pragma unroll
    for (int o = 32; o; o >>= 1) {
        sc += __shfl_xor(sc, o);
        ms += __shfl_xor(ms, o);
    }

    // ---- CRF forward ----
    float et[32];
#pragma unroll
    for (int i = 0; i < 32; ++i) et[i] = __expf(trans[i * LL + j]);

    const float a0 = startv[j] + emit[(size_t)b_ * LL + j];
    float M = a0;
    M = fmaxf(M, __shfl_xor(M, 16));
    M = fmaxf(M, __shfl_xor(M, 8));
    M = fmaxf(M, __shfl_xor(M, 4));
    M = fmaxf(M, __shfl_xor(M, 2));
    M = fmaxf(M, __shfl_xor(M, 1));
    float A = __expf(a0 - M);
    float logsc = M;

    float e_nx = emit[((size_t)1 * BB + b_) * LL + j];
    int   m_nx = charr[b_ * TT + 1];

    for (int t = 1; t < TT; ++t) {
        const float ee = __expf(e_nx);       // off critical chain (prefetched)
        const int m_cur = m_nx;
        if (t + 1 < TT) {
            e_nx = emit[((size_t)(t + 1) * BB + b_) * LL + j];
            m_nx = charr[b_ * TT + t + 1];
        }
        float s0 = 0.f, s1 = 0.f, s2 = 0.f, s3 = 0.f;
#pragma unroll
        for (int i = 0; i < 32; i += 4) {
            s0 = fmaf(__int_as_float(__builtin_amdgcn_readlane(__float_as_int(A), i    )), et[i    ], s0);
            s1 = fmaf(__int_as_float(__builtin_amdgcn_readlane(__float_as_int(A), i + 1)), et[i + 1], s1);
            s2 = fmaf(__int_as_float(__builtin_amdgcn_readlane(__float_as_int(A), i + 2)), et[i + 2], s2);
            s3 = fmaf(__int_as_float(__builtin_amdgcn_readlane(__float_as_int(A), i + 3)), et[i + 3], s3);
        }
        const float Anew = ((s0 + s1) + (s2 + s3)) * ee;
        A = (m_cur > 0) ? Anew : A;
        if ((t & 7) == 0) {                  // renorm every 8 steps
            float S = A;
            S = fmaxf(S, __shfl_xor(S, 16));
            S = fmaxf(S, __shfl_xor(S, 8));
            S = fmaxf(S, __shfl_xor(S, 4));
            S = fmaxf(S, __shfl_xor(S, 2));
            S = fmaxf(S, __shfl_xor(S, 1));
            A *= __builtin_amdgcn_rcpf(S);
            logsc += __logf(S);
        }
    }
    // finalize: alpha_j = log(A_j) + logsc; logZ = LSE_j(alpha_j + end_j)
    const float z = __logf(A) + logsc + endv[j];
    float Mz = z;
    Mz = fmaxf(Mz, __shfl_xor(Mz, 16));
    Mz = fmaxf(Mz, __shfl_xor(Mz, 8));
    Mz = fmaxf(Mz, __shfl_xor(Mz, 4));
    Mz = fmaxf(Mz, __shfl_xor(Mz, 2));
    Mz = fmaxf(Mz, __shfl_xor(Mz, 1));
    float sz = __expf(z - Mz);
    sz += __shfl_xor(sz, 16);
    sz += __shfl_xor(sz, 8);
    sz += __shfl_xor(sz, 4);
    sz += __shfl_xor(sz, 2);
    sz += __shfl_xor(sz, 1);
    if (tid == 0) {
        const float logZ = Mz + __logf(sz);
        int last = ms - 1;
        if (last < 0) last = 0;
        const float gold = startv[y[b_ * TT]] + sc + endv[y[b_ * TT + last]];
        atomicAdd(out, logZ - gold);
    }
}

extern "C" void kernel_launch(void* const* d_in, const int* in_sizes, int n_in,
                              void* d_out, int out_size, void* d_ws, size_t ws_size,
                              hipStream_t stream) {
    (void)in_sizes; (void)n_in; (void)out_size; (void)ws_size;
    const int*   word  = (const int*)d_in[0];
    const int*   charr = (const int*)d_in[1];
    const int*   yv    = (const int*)d_in[2];
    const float* wemb  = (const float*)d_in[3];
    const float* cemb  = (const float*)d_in[4];
    const float* Wihf  = (const float*)d_in[5];
    const float* Whhf  = (const float*)d_in[6];
    const float* bf    = (const float*)d_in[7];
    const float* Wihb  = (const float*)d_in[8];
    const float* Whhb  = (const float*)d_in[9];
    const float* bb    = (const float*)d_in[10];
    const float* Wout  = (const float*)d_in[11];
    const float* bout  = (const float*)d_in[12];
    const float* trans = (const float*)d_in[13];
    const float* startv= (const float*)d_in[14];
    const float* endv  = (const float*)d_in[15];

    float* ws    = (float*)d_ws;
    float* xpf   = ws;                          // [T][B][512] f32
    float* xpb   = xpf + (size_t)TT * BB * G4;
    __fp16* hf16 = (__fp16*)(xpb + (size_t)TT * BB * G4);  // [T][B][128] f16
    __fp16* hb16 = hf16 + (size_t)TT * BB * HH;
    float* emit  = (float*)(hb16 + (size_t)TT * BB * HH);  // [T][B][32] f32

    k_inproj<<<dim3(128, 4), 512, 0, stream>>>(word, charr, wemb, cemb,
                                               Wihf, bf, Wihb, bb, xpf, xpb,
                                               (float*)d_out);
    k_lstm<<<64, 512, 0, stream>>>(xpf, xpb, Whhf, Whhb, hf16, hb16);
    k_emit<<<TT, 1024, 0, stream>>>(hf16, hb16, Wout, bout, charr, emit);
    k_crf<<<32, 64, 0, stream>>>(emit, charr, yv, trans, startv, endv,
                                 (float*)d_out);
}